// Round 5
// baseline (394.418 us; speedup 1.0000x reference)
//
#include <hip/hip_runtime.h>
#include <stdint.h>

// CAFormer fused block, MI355X gfx950.
// I/O: all inputs fp32, d_out fp32. Internal intermediates bf16.
// R5: k_attn restructured — no scattered global reads. dir1 PV is role-swapped
// (O_v = V * P^T: A = V rows direct, B = Pbuf rows, direct coalesced store);
// transposed operands (dir1-S Q/K, dir0-PV V) are LDS-transpose-staged with
// coalesced uint4 reads + byte_perm + swizzled ds_write_b64.
// ws layout (~160.0 MB):
//   qkv bf16 [4][192][65536] @ 0          (100663296 B)
//   oh  bf16 [4][64][65536]  @ 100663296  (33554432 B)
//   ov  bf16                 @ 134217728  (33554432 B)
//   f32 scratch @ 167772160: gxsum[256] cwaw[8] rnorm[512]

typedef unsigned short u16;
typedef __attribute__((ext_vector_type(8))) short bf16x8;
typedef __attribute__((ext_vector_type(4))) float f32x4;

#define DEV static __device__ __forceinline__

DEV u16 f2bf(float f) {
  unsigned u = __float_as_uint(f);
  return (u16)((u + 0x7fffu + ((u >> 16) & 1u)) >> 16);
}
DEV float bf2f(u16 h) { return __uint_as_float(((unsigned)h) << 16); }

// ---------------- gating: per-(b,c) spatial sum of x ----------------
__global__ void k_gx(const float* __restrict__ x, float* __restrict__ gxsum) {
  int bc = blockIdx.x, t = threadIdx.x;
  const float4* p = (const float4*)(x + ((size_t)bc << 16));
  float s = 0.f;
  for (int i = 0; i < 64; ++i) { float4 v = p[t + 256 * i]; s += v.x + v.y + v.z + v.w; }
  for (int off = 32; off; off >>= 1) s += __shfl_down(s, off);
  __shared__ float lds[4];
  if ((t & 63) == 0) lds[t >> 6] = s;
  __syncthreads();
  if (t == 0) gxsum[bc] = lds[0] + lds[1] + lds[2] + lds[3];
}

// ---------------- gating MLP -> cw/aw per batch ----------------
__global__ void k_gate(const float* __restrict__ gxsum, const float* __restrict__ g1w,
                       const float* __restrict__ g1b, const float* __restrict__ g2w,
                       const float* __restrict__ g2b, float* __restrict__ cwaw) {
  __shared__ float h1[4][16];
  int t = threadIdx.x;
  int b = t >> 4, j = t & 15;
  float a = g1b[j];
  for (int c = 0; c < 64; ++c) a += g1w[j * 64 + c] * gxsum[b * 64 + c] * (1.f / 65536.f);
  h1[b][j] = fmaxf(a, 0.f);
  __syncthreads();
  if (t < 4) {
    float l0 = g2b[0], l1 = g2b[1];
    for (int k = 0; k < 16; ++k) { l0 += g2w[k] * h1[t][k]; l1 += g2w[16 + k] * h1[t][k]; }
    float m = fmaxf(l0, l1);
    float e0 = __expf(l0 - m), e1 = __expf(l1 - m);
    float inv = 1.f / (e0 + e1);
    cwaw[t * 2 + 0] = e0 * inv;  // conv weight
    cwaw[t * 2 + 1] = e1 * inv;  // attn weight
  }
}

// ---------------- qkv projection as MFMA GEMM: [192x64] x [64x128px] ----------------
__global__ __launch_bounds__(256) void k_qkv(const float* __restrict__ x,
                                             const float* __restrict__ wqkv,
                                             u16* __restrict__ qkv) {
  __shared__ u16 Ws[192 * 72];  // A: [row][ch]
  __shared__ u16 Xs[128 * 72];  // B^T: [px][ch]
  int t = threadIdx.x;
  int b = blockIdx.x >> 9;
  int p0 = (blockIdx.x & 511) << 7;

  {
    int row = t >> 2, c0 = (t & 3) << 4;
#pragma unroll
    for (int i = 0; i < 3; ++i) {
      int r = i * 64 + row;
      const float* src = wqkv + r * 64 + c0;
      unsigned pk[8];
#pragma unroll
      for (int j = 0; j < 8; ++j)
        pk[j] = (unsigned)f2bf(src[2 * j]) | ((unsigned)f2bf(src[2 * j + 1]) << 16);
      uint4* dst = (uint4*)&Ws[r * 72 + c0];
      dst[0] = make_uint4(pk[0], pk[1], pk[2], pk[3]);
      dst[1] = make_uint4(pk[4], pk[5], pk[6], pk[7]);
    }
  }
  {
    int p = t & 127, ch = t >> 7;
    const float* xb = x + ((size_t)(b * 64) << 16) + p0 + p;
#pragma unroll
    for (int i = 0; i < 32; ++i) {
      int c = 2 * i + ch;
      Xs[p * 72 + c] = f2bf(xb[(size_t)c << 16]);
    }
  }
  __syncthreads();

  int w = t >> 6, l = t & 63, q = l >> 4, cl = l & 15;
  bf16x8 af[3][2];
#pragma unroll
  for (int g = 0; g < 3; ++g)
#pragma unroll
    for (int k = 0; k < 2; ++k)
      af[g][k] = *(const bf16x8*)&Ws[(w * 48 + g * 16 + cl) * 72 + k * 32 + q * 8];

  f32x4 acc[3][8];
  f32x4 zero = {0.f, 0.f, 0.f, 0.f};
#pragma unroll
  for (int g = 0; g < 3; ++g)
#pragma unroll
    for (int j = 0; j < 8; ++j) acc[g][j] = zero;

  for (int j = 0; j < 8; ++j) {
    bf16x8 b0 = *(const bf16x8*)&Xs[(j * 16 + cl) * 72 + q * 8];
    bf16x8 b1 = *(const bf16x8*)&Xs[(j * 16 + cl) * 72 + 32 + q * 8];
#pragma unroll
    for (int g = 0; g < 3; ++g) {
      acc[g][j] = __builtin_amdgcn_mfma_f32_16x16x32_bf16(af[g][0], b0, acc[g][j], 0, 0, 0);
      acc[g][j] = __builtin_amdgcn_mfma_f32_16x16x32_bf16(af[g][1], b1, acc[g][j], 0, 0, 0);
    }
  }
  u16* outb = qkv + ((size_t)(b * 192) << 16) + p0;
  for (int g = 0; g < 3; ++g) {
    int rowb = w * 48 + g * 16 + q * 4;
#pragma unroll
    for (int r = 0; r < 4; ++r) {
      u16* orow = outb + ((size_t)(rowb + r) << 16);
#pragma unroll
      for (int j = 0; j < 8; ++j) orow[j * 16 + cl] = f2bf(acc[g][j][r]);
    }
  }
}

// ---------------- 1/||plane|| for q,k channels ----------------
__global__ void k_rnorm(const u16* __restrict__ qkv, float* __restrict__ rnorm) {
  int b = blockIdx.x >> 7, ch = blockIdx.x & 127;
  const uint2* p2 = (const uint2*)(qkv + ((size_t)(b * 192 + ch) << 16));
  int t = threadIdx.x;
  float s = 0.f;
  for (int i = 0; i < 64; ++i) {
    uint2 v = p2[t + 256 * i];
    float a = bf2f(v.x & 0xffff), bq = bf2f(v.x >> 16);
    float c = bf2f(v.y & 0xffff), d = bf2f(v.y >> 16);
    s += a * a + bq * bq + c * c + d * d;
  }
  for (int off = 32; off; off >>= 1) s += __shfl_down(s, off);
  __shared__ float lds[4];
  if ((t & 63) == 0) lds[t >> 6] = s;
  __syncthreads();
  if (t == 0) {
    float tot = lds[0] + lds[1] + lds[2] + lds[3];
    rnorm[blockIdx.x] = 1.f / fmaxf(sqrtf(tot), 1e-12f);
  }
}

// ---------------- depthwise 3x3+5x5 conv, writes cw*conv to d_out ----------------
__global__ void k_conv(const float* __restrict__ x, const float* __restrict__ w3,
                       const float* __restrict__ b3, const float* __restrict__ w5,
                       const float* __restrict__ b5, const float* __restrict__ cwaw,
                       float* __restrict__ outmix) {
  int rt = blockIdx.x & 31, bc = blockIdx.x >> 5, c = bc & 63, b = bc >> 6;
  int r0 = rt * 8;
  const float* xp = x + ((size_t)bc << 16);
  __shared__ float xs[12][256];
  int y = threadIdx.x;
  for (int rr = 0; rr < 12; ++rr) {
    int gr = r0 - 2 + rr;
    xs[rr][y] = (gr >= 0 && gr < 256) ? xp[(size_t)gr * 256 + y] : 0.f;
  }
  __syncthreads();
  float W3[9], W5[25];
#pragma unroll
  for (int i = 0; i < 9; ++i) W3[i] = w3[c * 9 + i];
#pragma unroll
  for (int i = 0; i < 25; ++i) W5[i] = w5[c * 25 + i];
  float bias = b3[c] + b5[c];
  float cw = cwaw[b * 2];
  float* op = outmix + ((size_t)bc << 16);
  for (int k = 0; k < 8; ++k) {
    float a = bias;
#pragma unroll
    for (int di = 0; di < 3; ++di)
#pragma unroll
      for (int dj = 0; dj < 3; ++dj) {
        int yy = y + dj - 1;
        float xv = (yy >= 0 && yy < 256) ? xs[k + 1 + di][yy] : 0.f;
        a += W3[di * 3 + dj] * xv;
      }
#pragma unroll
    for (int di = 0; di < 5; ++di)
#pragma unroll
      for (int dj = 0; dj < 5; ++dj) {
        int yy = y + dj - 2;
        float xv = (yy >= 0 && yy < 256) ? xs[k + di][yy] : 0.f;
        a += W5[di * 5 + dj] * xv;
      }
    op[(size_t)(r0 + k) * 256 + y] = cw * a;
  }
}

// ======== k_attn helpers: LDS transpose staging with 8-elem XOR swizzle ========
// Logical element (col n, k) lives at T[n*40 + ((k>>3)^((n>>3)&3))*8 + (k&7)].

// stage src[y0..y0+31][0..255] -> T[col][k] (256 cols), swizzled
DEV void stage_T256(const u16* __restrict__ src, int y0, u16* T, int t) {
  int q4 = t >> 5;            // y-quad: yrel = q4*4 + rr
  int c0 = (t & 31) * 8;
  uint4 r0v = *(const uint4*)&src[(size_t)(y0 + q4 * 4 + 0) * 256 + c0];
  uint4 r1v = *(const uint4*)&src[(size_t)(y0 + q4 * 4 + 1) * 256 + c0];
  uint4 r2v = *(const uint4*)&src[(size_t)(y0 + q4 * 4 + 2) * 256 + c0];
  uint4 r3v = *(const uint4*)&src[(size_t)(y0 + q4 * 4 + 3) * 256 + c0];
  const unsigned* a0 = (const unsigned*)&r0v;
  const unsigned* a1 = (const unsigned*)&r1v;
  const unsigned* a2 = (const unsigned*)&r2v;
  const unsigned* a3 = (const unsigned*)&r3v;
#pragma unroll
  for (int jj = 0; jj < 8; ++jj) {
    unsigned sel = (jj & 1) ? 0x7632u : 0x5410u;
    unsigned lo = __byte_perm(a0[jj >> 1], a1[jj >> 1], sel);
    unsigned hi = __byte_perm(a2[jj >> 1], a3[jj >> 1], sel);
    int col = c0 + jj;
    int off = col * 40 + ((((q4 >> 1) ^ ((col >> 3) & 3)) << 3) | ((q4 & 1) << 2));
    *(uint2*)&T[off] = make_uint2(lo, hi);
  }
}

// stage src[y0..y0+31][r0..r0+63] -> T[col][k] (64 cols), swizzled
DEV void stage_T64(const u16* __restrict__ src, int y0, int r0, u16* T, int t) {
  int yrel = t >> 3, c0 = (t & 7) * 8;
  uint4 v = *(const uint4*)&src[(size_t)(y0 + yrel) * 256 + r0 + c0];
  const unsigned* a = (const unsigned*)&v;
#pragma unroll
  for (int jj = 0; jj < 8; ++jj) {
    unsigned d = a[jj >> 1];
    u16 val = (jj & 1) ? (u16)(d >> 16) : (u16)(d & 0xffff);
    int col = c0 + jj;
    T[col * 40 + ((((yrel >> 3) ^ ((col >> 3) & 3)) << 3) | (yrel & 7))] = val;
  }
}

DEV bf16x8 read_sw(const u16* T, int n, int q) {
  return *(const bf16x8*)&T[n * 40 + ((q ^ ((n >> 3) & 3)) << 3)];
}

// ---------------- axial attention, MFMA bf16 ----------------
// block = (b, c, dir, rowtile of 64).
// dir0: S = Q K^T (direct), PV: A = Pbuf rows, B = Vt staged, store direct.
// dir1: S from staged Qt/Kt; PV role-swapped: O_v = V * P^T (A = V rows direct,
//       B = Pbuf rows), store direct.
__global__ __launch_bounds__(256) void k_attn(
    const u16* __restrict__ qkv, const float* __restrict__ rnorm,
    const float* __restrict__ scale, u16* __restrict__ oh, u16* __restrict__ ov) {
  __shared__ __align__(16) unsigned char smem[60416];
  u16* Qt = (u16*)smem;                  // dir1 S: [64][40]
  u16* Kt = (u16*)(smem + 5120);         // dir1 S: [256][40]
  u16* Vt = (u16*)smem;                  // dir0 PV: [256][40]
  u16* Pbuf = (u16*)(smem + 25600);      // [64][264]
  float* red = (float*)(smem + 59392);   // [4][64]

  int t = threadIdx.x;
  int w = t >> 6, l = t & 63, q = l >> 4, cl = l & 15;
  int idx = blockIdx.x;
  int rt = idx & 3, dir = (idx >> 2) & 1, c = (idx >> 3) & 63, b = idx >> 9;
  int r0 = rt << 6;

  const size_t P = 65536;
  const u16* Qp = qkv + (size_t)(b * 192 + c) * P;
  const u16* Kp = qkv + (size_t)(b * 192 + 64 + c) * P;
  const u16* Vp = qkv + (size_t)(b * 192 + 128 + c) * P;

  float sc = rnorm[b * 128 + c] * rnorm[b * 128 + 64 + c] * scale[c >> 3];

  f32x4 Sa[4][4];
  f32x4 zero = {0.f, 0.f, 0.f, 0.f};
#pragma unroll
  for (int i = 0; i < 4; ++i)
#pragma unroll
    for (int j = 0; j < 4; ++j) Sa[i][j] = zero;

  // ---- S phase: 8 k-windows of 32 ----
  if (dir == 0) {
    for (int yw = 0; yw < 8; ++yw) {
      int y0 = yw << 5;
      bf16x8 af[4], bfr[4];
#pragma unroll
      for (int i = 0; i < 4; ++i)
        af[i] = *(const bf16x8*)&Qp[(size_t)(r0 + i * 16 + cl) * 256 + y0 + q * 8];
#pragma unroll
      for (int j = 0; j < 4; ++j)
        bfr[j] = *(const bf16x8*)&Kp[(size_t)(w * 64 + j * 16 + cl) * 256 + y0 + q * 8];
#pragma unroll
      for (int i = 0; i < 4; ++i)
#pragma unroll
        for (int j = 0; j < 4; ++j)
          Sa[i][j] = __builtin_amdgcn_mfma_f32_16x16x32_bf16(af[i], bfr[j], Sa[i][j], 0, 0, 0);
    }
  } else {
    for (int yw = 0; yw < 8; ++yw) {
      int y0 = yw << 5;
      stage_T64(Qp, y0, r0, Qt, t);
      stage_T256(Kp, y0, Kt, t);
      __syncthreads();
      bf16x8 af[4], bfr[4];
#pragma unroll
      for (int i = 0; i < 4; ++i) af[i] = read_sw(Qt, i * 16 + cl, q);
#pragma unroll
      for (int j = 0; j < 4; ++j) bfr[j] = read_sw(Kt, w * 64 + j * 16 + cl, q);
#pragma unroll
      for (int i = 0; i < 4; ++i)
#pragma unroll
        for (int j = 0; j < 4; ++j)
          Sa[i][j] = __builtin_amdgcn_mfma_f32_16x16x32_bf16(af[i], bfr[j], Sa[i][j], 0, 0, 0);
      __syncthreads();
    }
  }

  // ---- softmax over cols (rows = i*16+q*4+r, cols = w*64+j*16+cl) ----
#pragma unroll
  for (int i = 0; i < 4; ++i)
#pragma unroll
    for (int j = 0; j < 4; ++j) Sa[i][j] *= sc;

  float mx[4][4], sm[4][4];
#pragma unroll
  for (int i = 0; i < 4; ++i)
#pragma unroll
    for (int r = 0; r < 4; ++r) {
      float m = fmaxf(fmaxf(Sa[i][0][r], Sa[i][1][r]), fmaxf(Sa[i][2][r], Sa[i][3][r]));
#pragma unroll
      for (int off = 1; off < 16; off <<= 1) m = fmaxf(m, __shfl_xor(m, off));
      mx[i][r] = m;
    }
  if (cl == 0) {
#pragma unroll
    for (int i = 0; i < 4; ++i)
#pragma unroll
      for (int r = 0; r < 4; ++r) red[w * 64 + i * 16 + q * 4 + r] = mx[i][r];
  }
  __syncthreads();
#pragma unroll
  for (int i = 0; i < 4; ++i)
#pragma unroll
    for (int r = 0; r < 4; ++r) {
      int rho = i * 16 + q * 4 + r;
      mx[i][r] = fmaxf(fmaxf(red[rho], red[64 + rho]), fmaxf(red[128 + rho], red[192 + rho]));
    }
  __syncthreads();
#pragma unroll
  for (int i = 0; i < 4; ++i)
#pragma unroll
    for (int r = 0; r < 4; ++r) {
      float s0 = 0.f;
#pragma unroll
      for (int j = 0; j < 4; ++j) {
        float e = __expf(Sa[i][j][r] - mx[i][r]);
        Sa[i][j][r] = e;
        s0 += e;
      }
#pragma unroll
      for (int off = 1; off < 16; off <<= 1) s0 += __shfl_xor(s0, off);
      sm[i][r] = s0;
    }
  if (cl == 0) {
#pragma unroll
    for (int i = 0; i < 4; ++i)
#pragma unroll
      for (int r = 0; r < 4; ++r) red[w * 64 + i * 16 + q * 4 + r] = sm[i][r];
  }
  __syncthreads();
#pragma unroll
  for (int i = 0; i < 4; ++i)
#pragma unroll
    for (int r = 0; r < 4; ++r) {
      int rho = i * 16 + q * 4 + r;
      sm[i][r] = 1.f / (red[rho] + red[64 + rho] + red[128 + rho] + red[192 + rho]);
    }
  // P -> Pbuf row-major [row 0..63][col 0..255]
#pragma unroll
  for (int i = 0; i < 4; ++i)
#pragma unroll
    for (int r = 0; r < 4; ++r) {
      int rho = i * 16 + q * 4 + r;
#pragma unroll
      for (int j = 0; j < 4; ++j)
        Pbuf[rho * 264 + w * 64 + j * 16 + cl] = f2bf(Sa[i][j][r] * sm[i][r]);
    }
  __syncthreads();

  f32x4 Oa[4][4];
#pragma unroll
  for (int i = 0; i < 4; ++i)
#pragma unroll
    for (int j = 0; j < 4; ++j) Oa[i][j] = zero;

  if (dir == 0) {
    // O = P V: A = Pbuf rows (M=64 tile rows), B = V^T staged (N=256 y-cols)
    for (int zw = 0; zw < 8; ++zw) {
      int z0 = zw << 5;
      stage_T256(Vp, z0, Vt, t);
      __syncthreads();
      bf16x8 af[4], bfr[4];
#pragma unroll
      for (int i = 0; i < 4; ++i)
        af[i] = *(const bf16x8*)&Pbuf[(i * 16 + cl) * 264 + z0 + q * 8];
#pragma unroll
      for (int j = 0; j < 4; ++j) bfr[j] = read_sw(Vt, w * 64 + j * 16 + cl, q);
#pragma unroll
      for (int i = 0; i < 4; ++i)
#pragma unroll
        for (int j = 0; j < 4; ++j)
          Oa[i][j] = __builtin_amdgcn_mfma_f32_16x16x32_bf16(af[i], bfr[j], Oa[i][j], 0, 0, 0);
      __syncthreads();
    }
    u16* op = oh + (size_t)(b * 64 + c) * P;
#pragma unroll
    for (int i = 0; i < 4; ++i)
#pragma unroll
      for (int j = 0; j < 4; ++j)
#pragma unroll
        for (int r = 0; r < 4; ++r)
          op[(size_t)(r0 + i * 16 + q * 4 + r) * 256 + w * 64 + j * 16 + cl] = f2bf(Oa[i][j][r]);
  } else {
    // O_v = V P^T: A = V rows (M=256 y-rows), B = Pbuf rows (N=64 tile cols)
    for (int xw = 0; xw < 8; ++xw) {
      int x0 = xw << 5;
      bf16x8 af[4], bfr[4];
#pragma unroll
      for (int i = 0; i < 4; ++i)
        af[i] = *(const bf16x8*)&Vp[(size_t)(w * 64 + i * 16 + cl) * 256 + x0 + q * 8];
#pragma unroll
      for (int j = 0; j < 4; ++j)
        bfr[j] = *(const bf16x8*)&Pbuf[(j * 16 + cl) * 264 + x0 + q * 8];
#pragma unroll
      for (int i = 0; i < 4; ++i)
#pragma unroll
        for (int j = 0; j < 4; ++j)
          Oa[i][j] = __builtin_amdgcn_mfma_f32_16x16x32_bf16(af[i], bfr[j], Oa[i][j], 0, 0, 0);
    }
    u16* op = ov + (size_t)(b * 64 + c) * P;
#pragma unroll
    for (int i = 0; i < 4; ++i)
#pragma unroll
      for (int j = 0; j < 4; ++j)
#pragma unroll
        for (int r = 0; r < 4; ++r)
          op[(size_t)(w * 64 + i * 16 + q * 4 + r) * 256 + r0 + j * 16 + cl] = f2bf(Oa[i][j][r]);
  }
}

// ---------------- mix + 64x64 projection as MFMA GEMM, in place on d_out ----------------
__global__ __launch_bounds__(256) void k_final(
    float* __restrict__ dout, const u16* __restrict__ oh, const u16* __restrict__ ov,
    const float* __restrict__ wp, const float* __restrict__ bp,
    const float* __restrict__ cwaw) {
  __shared__ u16 Ms[256 * 72];  // B^T: [px][ch]
  __shared__ u16 Ws[64 * 72];   // A: [row][ch]
  int t = threadIdx.x;
  int b = blockIdx.x >> 8;
  int p0 = (blockIdx.x & 255) << 8;
  float aw = cwaw[b * 2 + 1];

  {
    int row = t >> 2, c0 = (t & 3) << 4;
    const float* src = wp + row * 64 + c0;
    unsigned pk[8];
#pragma unroll
    for (int j = 0; j < 8; ++j)
      pk[j] = (unsigned)f2bf(src[2 * j]) | ((unsigned)f2bf(src[2 * j + 1]) << 16);
    uint4* dst = (uint4*)&Ws[row * 72 + c0];
    dst[0] = make_uint4(pk[0], pk[1], pk[2], pk[3]);
    dst[1] = make_uint4(pk[4], pk[5], pk[6], pk[7]);
  }
  {
    size_t base = ((size_t)(b * 64) << 16) + p0 + t;
    for (int c = 0; c < 64; ++c) {
      size_t off = base + ((size_t)c << 16);
      float m = dout[off] + aw * (bf2f(oh[off]) + bf2f(ov[off]));
      Ms[t * 72 + c] = f2bf(m);
    }
  }
  __syncthreads();

  int w = t >> 6, l = t & 63, q = l >> 4, cl = l & 15;
  bf16x8 af0 = *(const bf16x8*)&Ws[(w * 16 + cl) * 72 + q * 8];
  bf16x8 af1 = *(const bf16x8*)&Ws[(w * 16 + cl) * 72 + 32 + q * 8];

  f32x4 acc[16];
  f32x4 zero = {0.f, 0.f, 0.f, 0.f};
#pragma unroll
  for (int j = 0; j < 16; ++j) acc[j] = zero;

  for (int j = 0; j < 16; ++j) {
    bf16x8 b0 = *(const bf16x8*)&Ms[(j * 16 + cl) * 72 + q * 8];
    bf16x8 b1 = *(const bf16x8*)&Ms[(j * 16 + cl) * 72 + 32 + q * 8];
    acc[j] = __builtin_amdgcn_mfma_f32_16x16x32_bf16(af0, b0, acc[j], 0, 0, 0);
    acc[j] = __builtin_amdgcn_mfma_f32_16x16x32_bf16(af1, b1, acc[j], 0, 0, 0);
  }

  float bpv[4];
#pragma unroll
  for (int r = 0; r < 4; ++r) bpv[r] = bp[w * 16 + q * 4 + r];
  float* outb = dout + ((size_t)(b * 64) << 16) + p0;
#pragma unroll
  for (int r = 0; r < 4; ++r) {
    float* orow = outb + ((size_t)(w * 16 + q * 4 + r) << 16);
#pragma unroll
    for (int j = 0; j < 16; ++j) orow[j * 16 + cl] = acc[j][r] + bpv[r];
  }
}

extern "C" void kernel_launch(void* const* d_in, const int* in_sizes, int n_in,
                              void* d_out, int out_size, void* d_ws, size_t ws_size,
                              hipStream_t stream) {
  const float* x = (const float*)d_in[0];
  const float* w3 = (const float*)d_in[1];
  const float* b3 = (const float*)d_in[2];
  const float* w5 = (const float*)d_in[3];
  const float* b5 = (const float*)d_in[4];
  const float* wqkv = (const float*)d_in[5];
  const float* scale = (const float*)d_in[6];
  const float* g1w = (const float*)d_in[7];
  const float* g1b = (const float*)d_in[8];
  const float* g2w = (const float*)d_in[9];
  const float* g2b = (const float*)d_in[10];
  const float* wp = (const float*)d_in[11];
  const float* bp = (const float*)d_in[12];
  float* out = (float*)d_out;

  char* ws = (char*)d_ws;
  u16* qkv = (u16*)(ws);
  u16* ohb = (u16*)(ws + 100663296ull);
  u16* ovb = (u16*)(ws + 134217728ull);
  float* fs = (float*)(ws + 167772160ull);
  float* gxsum = fs;        // 256
  float* cwaw = fs + 256;   // 8
  float* rnorm = fs + 264;  // 512

  k_gx<<<256, 256, 0, stream>>>(x, gxsum);
  k_gate<<<1, 64, 0, stream>>>(gxsum, g1w, g1b, g2w, g2b, cwaw);
  k_qkv<<<2048, 256, 0, stream>>>(x, wqkv, qkv);
  k_rnorm<<<512, 256, 0, stream>>>(qkv, rnorm);
  k_conv<<<8192, 256, 0, stream>>>(x, w3, b3, w5, b5, cwaw, out);
  k_attn<<<2048, 256, 0, stream>>>(qkv, rnorm, scale, ohb, ovb);
  k_final<<<1024, 256, 0, stream>>>(out, ohb, ovb, wp, bp, cwaw);
}